// Round 8
// baseline (297478.687 us; speedup 1.0000x reference)
//
#include <hip/hip_runtime.h>
#include <hip/hip_bf16.h>
#include <hip/hip_cooperative_groups.h>
#include <stdint.h>
#include <stddef.h>
#include <math.h>

namespace cg = cooperative_groups;

#define HH 512
#define TT 512
#define BB 32
#define XH 3072   // 6*H
#define GH 2560   // 5*H
#define NWG 32    // scan workgroups
#define UPW 16    // units per scan WG
#define CL 128    // time-chunk length

__device__ __forceinline__ float sigm(float x){ return 1.f/(1.f+expf(-x)); }
__device__ __forceinline__ float tanh_f(float x){ return tanhf(x); }

__global__ void fill_sentinel_f(float* out, int n, float v){
  int i = blockIdx.x*blockDim.x + threadIdx.x;
  int stride = gridDim.x*blockDim.x;
  for (; i < n; i += stride) out[i] = v;
}

// ---------------- fp32 VALU GEMM: C[M,N] = A[M,K] @ W[N,K]^T + bias ----------
#define VBM 128
#define VBN 64
#define VBK 16

__global__ __launch_bounds__(256)
void gemm_valu(const float* __restrict__ A, const float* __restrict__ W,
               const float* __restrict__ bias, float* __restrict__ C,
               int M, int N, int K)
{
  __shared__ float As[VBK][VBM];
  __shared__ float Ws[VBK][VBN];
  const int tid = threadIdx.x;
  const int tx = tid & 15, ty = tid >> 4;
  const int gm = blockIdx.y, gn = blockIdx.x;
  float acc[8][4] = {};
  for (int k0 = 0; k0 < K; k0 += VBK){
    __syncthreads();
    {
      int row = tid >> 1, kc = (tid & 1)*8;
      const float* src = A + (size_t)(gm*VBM + row)*K + k0 + kc;
      float4 v0 = *(const float4*)(src);
      float4 v1 = *(const float4*)(src + 4);
      As[kc+0][row]=v0.x; As[kc+1][row]=v0.y; As[kc+2][row]=v0.z; As[kc+3][row]=v0.w;
      As[kc+4][row]=v1.x; As[kc+5][row]=v1.y; As[kc+6][row]=v1.z; As[kc+7][row]=v1.w;
    }
    {
      int row = tid >> 2, kc = (tid & 3)*4;
      float4 v = *(const float4*)(W + (size_t)(gn*VBN + row)*K + k0 + kc);
      Ws[kc+0][row]=v.x; Ws[kc+1][row]=v.y; Ws[kc+2][row]=v.z; Ws[kc+3][row]=v.w;
    }
    __syncthreads();
    #pragma unroll
    for (int kk = 0; kk < VBK; ++kk){
      float4 a0 = *(const float4*)&As[kk][ty*8];
      float4 a1 = *(const float4*)&As[kk][ty*8+4];
      float4 w  = *(const float4*)&Ws[kk][tx*4];
      float a[8] = {a0.x,a0.y,a0.z,a0.w,a1.x,a1.y,a1.z,a1.w};
      float wv[4] = {w.x,w.y,w.z,w.w};
      #pragma unroll
      for (int i=0;i<8;i++)
        #pragma unroll
        for (int j=0;j<4;j++)
          acc[i][j] = __builtin_fmaf(a[i], wv[j], acc[i][j]);
    }
  }
  #pragma unroll
  for (int i=0;i<8;i++){
    int row = gm*VBM + ty*8 + i;
    #pragma unroll
    for (int j=0;j<4;j++){
      int col = gn*VBN + tx*4 + j;
      C[(size_t)row*N + col] = acc[i][j] + bias[col];
    }
  }
}

// -------- all-fp32 VALU scan: 32 WGs x 512 thr, thread=(b,u) -----------------
__global__ __launch_bounds__(512)
void lstm_scan_simple(const float* __restrict__ xp,    // [CL*B][6H] f32 chunk-local
                      const float* __restrict__ whh,   // [5H][H] f32
                      const float* __restrict__ masks, // [T*B] f32
                      float* __restrict__ dst,         // [T*B][H] f32 (act or final out)
                      float* __restrict__ hT_out,      // [B][H] f32 (or null)
                      float* __restrict__ cT_out,      // [B][H] f32 (or null)
                      float* __restrict__ h_glob,      // [2][B][H] f32
                      float* __restrict__ st_h, float* __restrict__ st_c,
                      int reverse, int c0, int cl)
{
  cg::grid_group grid = cg::this_grid();
  __shared__ float hlds[BB*HH];
  const int g  = blockIdx.x;
  const int u0 = g*UPW;
  const int tid = threadIdx.x;
  const int b  = tid >> 4;
  const int uu = tid & 15;
  const int u  = u0 + uu;
  const float* w0 = whh + (size_t)(0*HH + u)*HH;
  const float* w1 = whh + (size_t)(1*HH + u)*HH;
  const float* w2 = whh + (size_t)(2*HH + u)*HH;
  const float* w3 = whh + (size_t)(3*HH + u)*HH;
  const float* w4 = whh + (size_t)(4*HH + u)*HH;

  float c_st, h_st;
  if (c0 == 0){ c_st = 0.f; h_st = 0.f; }
  else { h_st = st_h[(size_t)b*HH + u]; c_st = st_c[(size_t)b*HH + u]; }

  for (int sl = 0; sl < cl; ++sl){
    const int s  = c0 + sl;
    const int t  = reverse ? (TT-1-s) : s;
    const int lt = reverse ? (cl-1-sl) : sl;
    float p0=0.f, p1=0.f, p2=0.f, p3=0.f, p4=0.f;
    if (s > 0){
      const float* src = h_glob + (size_t)((s&1)^1)*(BB*HH);
      for (int i = tid*4; i < BB*HH; i += 512*4)
        *(float4*)&hlds[i] = *(const float4*)&src[i];
      __syncthreads();
      const float* hrow = &hlds[(size_t)b*HH];
      for (int k = 0; k < HH; k += 4){
        float4 hv = *(const float4*)&hrow[k];
        float4 a0 = *(const float4*)&w0[k];
        float4 a1 = *(const float4*)&w1[k];
        float4 a2 = *(const float4*)&w2[k];
        float4 a3 = *(const float4*)&w3[k];
        float4 a4 = *(const float4*)&w4[k];
        p0 = __builtin_fmaf(hv.x,a0.x,__builtin_fmaf(hv.y,a0.y,__builtin_fmaf(hv.z,a0.z,__builtin_fmaf(hv.w,a0.w,p0))));
        p1 = __builtin_fmaf(hv.x,a1.x,__builtin_fmaf(hv.y,a1.y,__builtin_fmaf(hv.z,a1.z,__builtin_fmaf(hv.w,a1.w,p1))));
        p2 = __builtin_fmaf(hv.x,a2.x,__builtin_fmaf(hv.y,a2.y,__builtin_fmaf(hv.z,a2.z,__builtin_fmaf(hv.w,a2.w,p2))));
        p3 = __builtin_fmaf(hv.x,a3.x,__builtin_fmaf(hv.y,a3.y,__builtin_fmaf(hv.z,a3.z,__builtin_fmaf(hv.w,a3.w,p3))));
        p4 = __builtin_fmaf(hv.x,a4.x,__builtin_fmaf(hv.y,a4.y,__builtin_fmaf(hv.z,a4.z,__builtin_fmaf(hv.w,a4.w,p4))));
      }
    }
    const size_t xb = ((size_t)lt*BB + b)*XH + u;
    float ig = sigm(p0 + xp[xb]);
    float fg = sigm(p1 + xp[xb +   HH] + 1.0f);
    float og = sigm(p2 + xp[xb + 2*HH]);
    float tg = sigm(p3 + xp[xb + 3*HH]);
    float jg = tanh_f(p4 + xp[xb + 4*HH]);
    float xk = xp[xb + 5*HH];
    float mm = masks[t*BB + b];
    float cn = fg*c_st + ig*jg;
    cn = mm*cn + (1.f-mm)*c_st;
    float hn = tg*og*tanh_f(cn) + (1.f-tg)*xk;
    hn = mm*hn + (1.f-mm)*h_st;
    c_st = cn; h_st = hn;
    h_glob[(size_t)(s&1)*(BB*HH) + (size_t)b*HH + u] = hn;
    dst[((size_t)t*BB + b)*HH + u] = hn;           // f32 store (act or d_out)
    if (sl < cl-1) grid.sync();
  }
  st_h[(size_t)b*HH + u] = h_st;
  st_c[(size_t)b*HH + u] = c_st;
  if (c0 + cl == TT){
    hT_out[(size_t)b*HH + u] = h_st;               // f32 store
    cT_out[(size_t)b*HH + u] = c_st;               // f32 store
  }
}

// ------------------------------- launch ---------------------------------------
extern "C" void kernel_launch(void* const* d_in, const int* in_sizes, int n_in,
                              void* d_out, int out_size, void* d_ws, size_t ws_size,
                              hipStream_t stream)
{
  // ---- robust input binding: identify tensors by element count --------------
  const float* x = nullptr; const float* masks = nullptr;
  const float* wih[4] = {}; const float* bih[4] = {}; const float* whh[4] = {};
  int nw = 0, nb = 0, nh = 0;
  for (int i = 0; i < n_in; ++i){
    const int sz = in_sizes[i];
    const float* p = (const float*)d_in[i];
    if      (sz == TT*BB*HH){ if (!x) x = p; }
    else if (sz == TT*BB)   { if (!masks) masks = p; }
    else if (sz == XH*HH)   { if (nw < 4) wih[nw++] = p; }
    else if (sz == XH)      { if (nb < 4) bih[nb++] = p; }
    else if (sz == GH*HH)   { if (nh < 4) whh[nh++] = p; }
  }
  float* out = (float*)d_out;   // reference outputs are float32 -> d_out is float*
  if (!x || !masks || nw != 4 || nb != 4 || nh != 4){
    fill_sentinel_f<<<512, 256, 0, stream>>>(out, out_size, 777.0f);
    return;
  }

  char* ws = (char*)d_ws;
  size_t off = 0;
  auto alloc = [&](size_t bytes)->void*{
    void* p = ws + off; off += (bytes + 255) & ~(size_t)255; return p;
  };
  float* act    = (float*)alloc((size_t)TT*BB*HH*4);   // 33.6 MB
  float* xproj  = (float*)alloc((size_t)CL*BB*XH*4);   // 50.3 MB
  float* h_glob = (float*)alloc((size_t)2*BB*HH*4);
  float* st_h   = (float*)alloc((size_t)BB*HH*4);
  float* st_c   = (float*)alloc((size_t)BB*HH*4);

  float* hn = out + (size_t)TT*BB*HH;
  float* cn = hn + (size_t)4*BB*HH;

  for (int L = 0; L < 4; ++L){
    const int rev = L & 1;
    for (int c = 0; c < TT/CL; ++c){
      const int c0  = c*CL;
      const int tlo = rev ? (TT - c0 - CL) : c0;
      const float* Ain = (L == 0 ? x : act) + (size_t)tlo*BB*HH;
      gemm_valu<<<dim3(XH/VBN, (CL*BB)/VBM), 256, 0, stream>>>(
          Ain, wih[L], bih[L], xproj, CL*BB, XH, HH);

      const float* xp_p  = xproj;
      const float* wh_p  = whh[L];
      const float* mk_p  = masks;
      float*       dst_p = (L == 3) ? out : act;
      float*       hT_p  = hn + (size_t)L*BB*HH;
      float*       cT_p  = cn + (size_t)L*BB*HH;
      float*       hg_p  = h_glob;
      float*       sh_p  = st_h;
      float*       sc_p  = st_c;
      int          rv    = rev;
      int          c0a   = c0;
      int          cla   = CL;
      void* args[12] = {&xp_p, &wh_p, &mk_p, &dst_p, &hT_p, &cT_p,
                        &hg_p, &sh_p, &sc_p, &rv, &c0a, &cla};
      hipLaunchCooperativeKernel((const void*)lstm_scan_simple, dim3(NWG), dim3(512),
                                 args, 0, stream);
    }
  }
}

// Round 10
// 25972.784 us; speedup vs baseline: 11.4535x; 11.4535x over previous
//
#include <hip/hip_runtime.h>
#include <hip/hip_bf16.h>
#include <stdint.h>
#include <stddef.h>
#include <math.h>

#define HH 512
#define TT 512
#define BB 32
#define XH 3072   // 6*H
#define GH 2560   // 5*H
#define NWG 32    // scan workgroups
#define UPW 16    // units per scan WG
#define CL 128    // time-chunk length
#define PADH 264  // padded h row stride (uints) in LDS

typedef __attribute__((ext_vector_type(2))) _Float16 half2v;

__device__ __forceinline__ float sigm(float x){ return 1.f/(1.f+expf(-x)); }
__device__ __forceinline__ float tanh_f(float x){ return tanhf(x); }

__global__ void fill_sentinel_f(float* out, int n, float v){
  int i = blockIdx.x*blockDim.x + threadIdx.x;
  int stride = gridDim.x*blockDim.x;
  for (; i < n; i += stride) out[i] = v;
}

// ---- pack whh f32 [5H][H] -> Wpk[wg][kq][gate][j][q] f16x2 (uint) -----------
__global__ void pack_whh(const float* __restrict__ whh, unsigned int* __restrict__ Wpk){
  int i = blockIdx.x*blockDim.x + threadIdx.x;
  const int total = NWG*64*5*16*4;
  if (i >= total) return;
  int q  = i & 3;
  int j  = (i >> 2) & 15;
  int gt = (i >> 6) % 5;
  int kq = ((i >> 6) / 5) & 63;
  int wg = i / (64*5*16*4);
  int u = wg*16 + j, r = gt*512 + u, k = kq*8 + q*2;
  half2v p;
  p[0] = (_Float16)whh[(size_t)r*HH + k];
  p[1] = (_Float16)whh[(size_t)r*HH + k + 1];
  Wpk[i] = __builtin_bit_cast(unsigned int, p);
}

// ---------------- fp32 VALU GEMM: C[M,N] = A[M,K] @ W[N,K]^T + bias ----------
#define VBM 128
#define VBN 64
#define VBK 16

__global__ __launch_bounds__(256)
void gemm_valu(const float* __restrict__ A, const float* __restrict__ W,
               const float* __restrict__ bias, float* __restrict__ C,
               int M, int N, int K)
{
  __shared__ float As[VBK][VBM];
  __shared__ float Ws[VBK][VBN];
  const int tid = threadIdx.x;
  const int tx = tid & 15, ty = tid >> 4;
  const int gm = blockIdx.y, gn = blockIdx.x;
  float acc[8][4] = {};
  for (int k0 = 0; k0 < K; k0 += VBK){
    __syncthreads();
    {
      int row = tid >> 1, kc = (tid & 1)*8;
      const float* src = A + (size_t)(gm*VBM + row)*K + k0 + kc;
      float4 v0 = *(const float4*)(src);
      float4 v1 = *(const float4*)(src + 4);
      As[kc+0][row]=v0.x; As[kc+1][row]=v0.y; As[kc+2][row]=v0.z; As[kc+3][row]=v0.w;
      As[kc+4][row]=v1.x; As[kc+5][row]=v1.y; As[kc+6][row]=v1.z; As[kc+7][row]=v1.w;
    }
    {
      int row = tid >> 2, kc = (tid & 3)*4;
      float4 v = *(const float4*)(W + (size_t)(gn*VBN + row)*K + k0 + kc);
      Ws[kc+0][row]=v.x; Ws[kc+1][row]=v.y; Ws[kc+2][row]=v.z; Ws[kc+3][row]=v.w;
    }
    __syncthreads();
    #pragma unroll
    for (int kk = 0; kk < VBK; ++kk){
      float4 a0 = *(const float4*)&As[kk][ty*8];
      float4 a1 = *(const float4*)&As[kk][ty*8+4];
      float4 w  = *(const float4*)&Ws[kk][tx*4];
      float a[8] = {a0.x,a0.y,a0.z,a0.w,a1.x,a1.y,a1.z,a1.w};
      float wv[4] = {w.x,w.y,w.z,w.w};
      #pragma unroll
      for (int i=0;i<8;i++)
        #pragma unroll
        for (int j=0;j<4;j++)
          acc[i][j] = __builtin_fmaf(a[i], wv[j], acc[i][j]);
    }
  }
  #pragma unroll
  for (int i=0;i<8;i++){
    int row = gm*VBM + ty*8 + i;
    #pragma unroll
    for (int j=0;j<4;j++){
      int col = gn*VBN + tx*4 + j;
      C[(size_t)row*N + col] = acc[i][j] + bias[col];
    }
  }
}

// -------- scan: 32 WGs x 512 thr; weights in LDS (f16), fdot2, custom barrier -
__global__ __launch_bounds__(512)
void lstm_scan_f16(const float* __restrict__ xp,          // [CL*B][6H] f32 chunk-local
                   const unsigned int* __restrict__ Wpk,  // packed f16 weights
                   const float* __restrict__ masks,       // [T*B] f32
                   float* __restrict__ dst,               // [T*B][H] f32
                   float* __restrict__ hT_out, float* __restrict__ cT_out,
                   unsigned short* __restrict__ hbuf,     // [2][B][H] f16
                   float* __restrict__ st_h, float* __restrict__ st_c,
                   int* __restrict__ cnt,                 // [TT] zeroed
                   int reverse, int c0, int cl)
{
  __shared__ __align__(16) unsigned int wlds[64*5*16*4];  // 80 KB
  __shared__ __align__(16) unsigned int hp2[BB*PADH];     // 33 KB
  const int g = blockIdx.x, tid = threadIdx.x;
  const int b = tid >> 4, j = tid & 15;
  const int u = g*UPW + j;

  // load this WG's weight slice into LDS once (immune to barrier L2 inv)
  {
    const uint4* src = (const uint4*)(Wpk + (size_t)g*(64*5*16*4));
    uint4* d4 = (uint4*)wlds;
    #pragma unroll
    for (int i = 0; i < 10; ++i) d4[tid + i*512] = src[tid + i*512];
  }
  float c_st, h_st;
  if (c0 == 0){ c_st = 0.f; h_st = 0.f; }
  else { h_st = st_h[(size_t)b*HH + u]; c_st = st_c[(size_t)b*HH + u]; }
  __syncthreads();

  for (int sl = 0; sl < cl; ++sl){
    const int s  = c0 + sl;
    const int t  = reverse ? (TT-1-s) : s;
    const int lt = reverse ? (cl-1-sl) : sl;
    // prefetch xp + mask early (independent of h)
    const size_t xb = ((size_t)lt*BB + b)*XH + u;
    float xi = xp[xb];
    float xf = xp[xb +   HH];
    float xo = xp[xb + 2*HH];
    float xg = xp[xb + 3*HH];
    float xj = xp[xb + 4*HH];
    float xk = xp[xb + 5*HH];
    float mm = masks[t*BB + b];

    float p0=0.f, p1=0.f, p2=0.f, p3=0.f, p4=0.f;
    if (s > 0){
      // stage prev h (f16, 32 KB) -> LDS with padded stride (conflict-free)
      const uint4* src = (const uint4*)(hbuf + (size_t)((s&1)^1)*(BB*HH));
      #pragma unroll
      for (int it = 0; it < 4; ++it){
        int i = tid + it*512;            // 2048 uint4 total
        int bb = i >> 6, c4 = i & 63;
        *(uint4*)&hp2[bb*PADH + c4*4] = src[i];
      }
      __syncthreads();
      const unsigned int* hrow = &hp2[b*PADH];
      #pragma unroll 8
      for (int kq = 0; kq < 64; ++kq){
        uint4 hv = *(const uint4*)&hrow[kq*4];
        half2v h0 = __builtin_bit_cast(half2v, hv.x);
        half2v h1 = __builtin_bit_cast(half2v, hv.y);
        half2v h2 = __builtin_bit_cast(half2v, hv.z);
        half2v h3 = __builtin_bit_cast(half2v, hv.w);
        const unsigned int* wb = &wlds[(kq*5*16 + j)*4];
        uint4 w;
        w = *(const uint4*)&wb[0*16*4];
        p0 = __builtin_amdgcn_fdot2(h0, __builtin_bit_cast(half2v, w.x), p0, false);
        p0 = __builtin_amdgcn_fdot2(h1, __builtin_bit_cast(half2v, w.y), p0, false);
        p0 = __builtin_amdgcn_fdot2(h2, __builtin_bit_cast(half2v, w.z), p0, false);
        p0 = __builtin_amdgcn_fdot2(h3, __builtin_bit_cast(half2v, w.w), p0, false);
        w = *(const uint4*)&wb[1*16*4];
        p1 = __builtin_amdgcn_fdot2(h0, __builtin_bit_cast(half2v, w.x), p1, false);
        p1 = __builtin_amdgcn_fdot2(h1, __builtin_bit_cast(half2v, w.y), p1, false);
        p1 = __builtin_amdgcn_fdot2(h2, __builtin_bit_cast(half2v, w.z), p1, false);
        p1 = __builtin_amdgcn_fdot2(h3, __builtin_bit_cast(half2v, w.w), p1, false);
        w = *(const uint4*)&wb[2*16*4];
        p2 = __builtin_amdgcn_fdot2(h0, __builtin_bit_cast(half2v, w.x), p2, false);
        p2 = __builtin_amdgcn_fdot2(h1, __builtin_bit_cast(half2v, w.y), p2, false);
        p2 = __builtin_amdgcn_fdot2(h2, __builtin_bit_cast(half2v, w.z), p2, false);
        p2 = __builtin_amdgcn_fdot2(h3, __builtin_bit_cast(half2v, w.w), p2, false);
        w = *(const uint4*)&wb[3*16*4];
        p3 = __builtin_amdgcn_fdot2(h0, __builtin_bit_cast(half2v, w.x), p3, false);
        p3 = __builtin_amdgcn_fdot2(h1, __builtin_bit_cast(half2v, w.y), p3, false);
        p3 = __builtin_amdgcn_fdot2(h2, __builtin_bit_cast(half2v, w.z), p3, false);
        p3 = __builtin_amdgcn_fdot2(h3, __builtin_bit_cast(half2v, w.w), p3, false);
        w = *(const uint4*)&wb[4*16*4];
        p4 = __builtin_amdgcn_fdot2(h0, __builtin_bit_cast(half2v, w.x), p4, false);
        p4 = __builtin_amdgcn_fdot2(h1, __builtin_bit_cast(half2v, w.y), p4, false);
        p4 = __builtin_amdgcn_fdot2(h2, __builtin_bit_cast(half2v, w.z), p4, false);
        p4 = __builtin_amdgcn_fdot2(h3, __builtin_bit_cast(half2v, w.w), p4, false);
      }
    }
    float ig = sigm(p0 + xi);
    float fg = sigm(p1 + xf + 1.0f);
    float og = sigm(p2 + xo);
    float tg = sigm(p3 + xg);
    float jg = tanh_f(p4 + xj);
    float cn = fg*c_st + ig*jg;
    cn = mm*cn + (1.f-mm)*c_st;
    float hn = tg*og*tanh_f(cn) + (1.f-tg)*xk;
    hn = mm*hn + (1.f-mm)*h_st;
    c_st = cn; h_st = hn;
    // publish h (f16) + output (f32)
    _Float16 hf = (_Float16)hn;
    hbuf[(size_t)(s&1)*(BB*HH) + (size_t)b*HH + u] = __builtin_bit_cast(unsigned short, hf);
    dst[((size_t)t*BB + b)*HH + u] = hn;

    if (sl < cl-1){
      __syncthreads();   // all lanes done reading hp2 & writing hbuf
      if (tid == 0){
        __hip_atomic_fetch_add(&cnt[s], 1, __ATOMIC_RELEASE, __HIP_MEMORY_SCOPE_AGENT);
        while (__hip_atomic_load(&cnt[s], __ATOMIC_ACQUIRE, __HIP_MEMORY_SCOPE_AGENT) < NWG)
          __builtin_amdgcn_s_sleep(1);
      }
      __syncthreads();
    }
  }
  st_h[(size_t)b*HH + u] = h_st;
  st_c[(size_t)b*HH + u] = c_st;
  if (c0 + cl == TT){
    hT_out[(size_t)b*HH + u] = h_st;
    cT_out[(size_t)b*HH + u] = c_st;
  }
}

// ------------------------------- launch ---------------------------------------
extern "C" void kernel_launch(void* const* d_in, const int* in_sizes, int n_in,
                              void* d_out, int out_size, void* d_ws, size_t ws_size,
                              hipStream_t stream)
{
  const float* x = nullptr; const float* masks = nullptr;
  const float* wih[4] = {}; const float* bih[4] = {}; const float* whh[4] = {};
  int nw = 0, nb = 0, nh = 0;
  for (int i = 0; i < n_in; ++i){
    const int sz = in_sizes[i];
    const float* p = (const float*)d_in[i];
    if      (sz == TT*BB*HH){ if (!x) x = p; }
    else if (sz == TT*BB)   { if (!masks) masks = p; }
    else if (sz == XH*HH)   { if (nw < 4) wih[nw++] = p; }
    else if (sz == XH)      { if (nb < 4) bih[nb++] = p; }
    else if (sz == GH*HH)   { if (nh < 4) whh[nh++] = p; }
  }
  float* out = (float*)d_out;
  if (!x || !masks || nw != 4 || nb != 4 || nh != 4){
    fill_sentinel_f<<<512, 256, 0, stream>>>(out, out_size, 777.0f);
    return;
  }

  char* ws = (char*)d_ws;
  size_t off = 0;
  auto alloc = [&](size_t bytes)->void*{
    void* p = ws + off; off += (bytes + 255) & ~(size_t)255; return p;
  };
  float*          act   = (float*)alloc((size_t)TT*BB*HH*4);           // 33.6 MB
  float*          xproj = (float*)alloc((size_t)CL*BB*XH*4);           // 50.3 MB
  unsigned int*   Wpk   = (unsigned int*)alloc((size_t)NWG*64*5*16*4*4); // 2.6 MB
  unsigned short* hbuf  = (unsigned short*)alloc((size_t)2*BB*HH*2);   // 64 KB
  float*          st_h  = (float*)alloc((size_t)BB*HH*4);
  float*          st_c  = (float*)alloc((size_t)BB*HH*4);
  int*            cnt   = (int*)alloc((size_t)4*TT*4);

  (void)hipMemsetAsync(cnt, 0, (size_t)4*TT*4, stream);

  float* hn = out + (size_t)TT*BB*HH;
  float* cn = hn + (size_t)4*BB*HH;

  for (int L = 0; L < 4; ++L){
    const int rev = L & 1;
    pack_whh<<<(NWG*64*5*16*4 + 255)/256, 256, 0, stream>>>(whh[L], Wpk);
    for (int c = 0; c < TT/CL; ++c){
      const int c0  = c*CL;
      const int tlo = rev ? (TT - c0 - CL) : c0;
      const float* Ain = (L == 0 ? x : act) + (size_t)tlo*BB*HH;
      gemm_valu<<<dim3(XH/VBN, (CL*BB)/VBM), 256, 0, stream>>>(
          Ain, wih[L], bih[L], xproj, CL*BB, XH, HH);

      const float*        xp_p  = xproj;
      const unsigned int* wp_p  = Wpk;
      const float*        mk_p  = masks;
      float*              dst_p = (L == 3) ? out : act;
      float*              hT_p  = hn + (size_t)L*BB*HH;
      float*              cT_p  = cn + (size_t)L*BB*HH;
      unsigned short*     hb_p  = hbuf;
      float*              sh_p  = st_h;
      float*              sc_p  = st_c;
      int*                ct_p  = cnt + L*TT;
      int                 rv    = rev;
      int                 c0a   = c0;
      int                 cla   = CL;
      void* args[13] = {&xp_p, &wp_p, &mk_p, &dst_p, &hT_p, &cT_p, &hb_p,
                        &sh_p, &sc_p, &ct_p, &rv, &c0a, &cla};
      hipLaunchCooperativeKernel((const void*)lstm_scan_f16, dim3(NWG), dim3(512),
                                 args, 0, stream);
    }
  }
}

// Round 11
// 23315.051 us; speedup vs baseline: 12.7591x; 1.1140x over previous
//
#include <hip/hip_runtime.h>
#include <hip/hip_bf16.h>
#include <stdint.h>
#include <stddef.h>
#include <math.h>

#define HH 512
#define TT 512
#define BB 32
#define XH 3072   // 6*H
#define GH 2560   // 5*H
#define NWG 32    // unit-partition WGs per group
#define UPW 16    // units per WG
#define CL 128    // time-chunk length
#define NGRP 8    // batch groups (XCD-local)
#define RPG 4     // batch rows per group

typedef __attribute__((ext_vector_type(2))) _Float16 half2v;

__device__ __forceinline__ float sigm(float x){ return 1.f/(1.f+expf(-x)); }
__device__ __forceinline__ float tanh_f(float x){ return tanhf(x); }
__device__ __forceinline__ float fdot2u(unsigned int h, unsigned int w, float acc){
  return __builtin_amdgcn_fdot2(__builtin_bit_cast(half2v, h),
                                __builtin_bit_cast(half2v, w), acc, false);
}

__global__ void fill_sentinel_f(float* out, int n, float v){
  int i = blockIdx.x*blockDim.x + threadIdx.x;
  int stride = gridDim.x*blockDim.x;
  for (; i < n; i += stride) out[i] = v;
}

// ---- pack whh f32 [5H][H] -> Wpk[wgi][kq][gate][j][q] f16x2 (uint) ----------
__global__ void pack_whh(const float* __restrict__ whh, unsigned int* __restrict__ Wpk){
  int i = blockIdx.x*blockDim.x + threadIdx.x;
  const int total = NWG*64*5*16*4;
  if (i >= total) return;
  int q  = i & 3;
  int j  = (i >> 2) & 15;
  int gt = (i >> 6) % 5;
  int kq = ((i >> 6) / 5) & 63;
  int wg = i / (64*5*16*4);
  int u = wg*16 + j, r = gt*512 + u, k = kq*8 + q*2;
  half2v p;
  p[0] = (_Float16)whh[(size_t)r*HH + k];
  p[1] = (_Float16)whh[(size_t)r*HH + k + 1];
  Wpk[i] = __builtin_bit_cast(unsigned int, p);
}

// ---------------- fp32 VALU GEMM: C[M,N] = A[M,K] @ W[N,K]^T + bias ----------
#define VBM 128
#define VBN 64
#define VBK 16

__global__ __launch_bounds__(256)
void gemm_valu(const float* __restrict__ A, const float* __restrict__ W,
               const float* __restrict__ bias, float* __restrict__ C,
               int M, int N, int K)
{
  __shared__ float As[VBK][VBM];
  __shared__ float Ws[VBK][VBN];
  const int tid = threadIdx.x;
  const int tx = tid & 15, ty = tid >> 4;
  const int gm = blockIdx.y, gn = blockIdx.x;
  float acc[8][4] = {};
  for (int k0 = 0; k0 < K; k0 += VBK){
    __syncthreads();
    {
      int row = tid >> 1, kc = (tid & 1)*8;
      const float* src = A + (size_t)(gm*VBM + row)*K + k0 + kc;
      float4 v0 = *(const float4*)(src);
      float4 v1 = *(const float4*)(src + 4);
      As[kc+0][row]=v0.x; As[kc+1][row]=v0.y; As[kc+2][row]=v0.z; As[kc+3][row]=v0.w;
      As[kc+4][row]=v1.x; As[kc+5][row]=v1.y; As[kc+6][row]=v1.z; As[kc+7][row]=v1.w;
    }
    {
      int row = tid >> 2, kc = (tid & 3)*4;
      float4 v = *(const float4*)(W + (size_t)(gn*VBN + row)*K + k0 + kc);
      Ws[kc+0][row]=v.x; Ws[kc+1][row]=v.y; Ws[kc+2][row]=v.z; Ws[kc+3][row]=v.w;
    }
    __syncthreads();
    #pragma unroll
    for (int kk = 0; kk < VBK; ++kk){
      float4 a0 = *(const float4*)&As[kk][ty*8];
      float4 a1 = *(const float4*)&As[kk][ty*8+4];
      float4 w  = *(const float4*)&Ws[kk][tx*4];
      float a[8] = {a0.x,a0.y,a0.z,a0.w,a1.x,a1.y,a1.z,a1.w};
      float wv[4] = {w.x,w.y,w.z,w.w};
      #pragma unroll
      for (int i=0;i<8;i++)
        #pragma unroll
        for (int j=0;j<4;j++)
          acc[i][j] = __builtin_fmaf(a[i], wv[j], acc[i][j]);
    }
  }
  #pragma unroll
  for (int i=0;i<8;i++){
    int row = gm*VBM + ty*8 + i;
    #pragma unroll
    for (int j=0;j<4;j++){
      int col = gn*VBN + tx*4 + j;
      C[(size_t)row*N + col] = acc[i][j] + bias[col];
    }
  }
}

// ---- scan v3: 256 WGs = 8 XCD-local groups(4 rows) x 32 unit-WGs(16 units) --
// barrier only among the 32 WGs of a group -> L2-local release/acquire.
__global__ __launch_bounds__(512)
void lstm_scan_v3(const float* __restrict__ xp,          // [CL*B][6H] f32 chunk-local
                  const unsigned int* __restrict__ Wpk,  // packed f16 weights
                  const float* __restrict__ masks,       // [T*B] f32
                  float* __restrict__ dst,               // [T*B][H] f32
                  float* __restrict__ hT_out, float* __restrict__ cT_out,
                  unsigned short* __restrict__ hxch,     // [2][B][H] f16
                  float* __restrict__ st_h, float* __restrict__ st_c,
                  int* __restrict__ cnt,                 // [TT][128] ints (zeroed)
                  int reverse, int c0, int cl)
{
  __shared__ __align__(16) unsigned int wlds[64*5*16*4];  // 80 KB
  __shared__ __align__(16) unsigned int hs[RPG*256];      // 4 rows x 512 f16 = 4 KB
  __shared__ float pre[RPG][5][16];                       // 1.25 KB
  const int g   = blockIdx.x & 7;        // batch group (XCD-local by dispatch rr)
  const int wgi = blockIdx.x >> 3;       // unit-partition index 0..31
  const int tid = threadIdx.x;

  // load this WG's weight slice into LDS once
  {
    const uint4* src = (const uint4*)(Wpk + (size_t)wgi*(64*5*16*4));
    uint4* d4 = (uint4*)wlds;
    #pragma unroll
    for (int i = 0; i < 10; ++i) d4[tid + i*512] = src[tid + i*512];
  }
  const int bl   = tid >> 7;             // local row 0..3
  const int t128 = tid & 127;
  const bool isDot = t128 < 80;
  const int gt = t128 >> 4;              // gate 0..4 (dot threads)
  const int uu = t128 & 15;
  const bool isPw = t128 < 16;           // pointwise: (bl, uu)
  const int b = g*RPG + bl;              // global batch row
  const int u = wgi*16 + uu;             // global unit

  float c_st = 0.f, h_st = 0.f;
  if (isPw && c0 != 0){
    h_st = st_h[(size_t)b*HH + u];
    c_st = st_c[(size_t)b*HH + u];
  }
  __syncthreads();   // wlds ready

  for (int sl = 0; sl < cl; ++sl){
    const int s  = c0 + sl;
    const int t  = reverse ? (TT-1-s) : s;
    const int lt = reverse ? (cl-1-sl) : sl;
    // pointwise threads prefetch xp + mask (independent of h)
    float xi=0,xf=0,xo=0,xg=0,xj=0,xk=0,mm=0;
    if (isPw){
      const size_t xb = ((size_t)lt*BB + b)*XH + u;
      xi = xp[xb];        xf = xp[xb +   HH];
      xo = xp[xb + 2*HH]; xg = xp[xb + 3*HH];
      xj = xp[xb + 4*HH]; xk = xp[xb + 5*HH];
      mm = masks[t*BB + b];
    }
    if (s > 0){
      // restage this group's 4 h rows (4 KB) from hxch
      const uint4* src = (const uint4*)(hxch + ((size_t)((s&1)^1)*BB + g*RPG)*HH);
      if (tid < 256) ((uint4*)hs)[tid] = src[tid];
      __syncthreads();
      if (isDot){
        const unsigned int* hrow = &hs[bl*256];
        const unsigned int* wrow = &wlds[(gt*16 + uu)*4];
        float a0=0.f,a1=0.f,a2=0.f,a3=0.f;
        #pragma unroll 8
        for (int kq = 0; kq < 64; ++kq){
          uint4 hv = *(const uint4*)&hrow[kq*4];
          uint4 wv = *(const uint4*)&wrow[(size_t)kq*320];
          a0 = fdot2u(hv.x, wv.x, a0);
          a1 = fdot2u(hv.y, wv.y, a1);
          a2 = fdot2u(hv.z, wv.z, a2);
          a3 = fdot2u(hv.w, wv.w, a3);
        }
        pre[bl][gt][uu] = (a0+a1)+(a2+a3);
      }
    }
    __syncthreads();
    if (isPw){
      float p0=0,p1=0,p2=0,p3=0,p4=0;
      if (s > 0){
        p0 = pre[bl][0][uu]; p1 = pre[bl][1][uu]; p2 = pre[bl][2][uu];
        p3 = pre[bl][3][uu]; p4 = pre[bl][4][uu];
      }
      float ig = sigm(p0 + xi);
      float fg = sigm(p1 + xf + 1.0f);
      float og = sigm(p2 + xo);
      float tg = sigm(p3 + xg);
      float jg = tanh_f(p4 + xj);
      float cn = fg*c_st + ig*jg;
      cn = mm*cn + (1.f-mm)*c_st;
      float hn = tg*og*tanh_f(cn) + (1.f-tg)*xk;
      hn = mm*hn + (1.f-mm)*h_st;
      c_st = cn; h_st = hn;
      _Float16 hf = (_Float16)hn;
      hxch[(size_t)(s&1)*BB*HH + (size_t)b*HH + u] = __builtin_bit_cast(unsigned short, hf);
      dst[((size_t)t*BB + b)*HH + u] = hn;
    }
    if (sl < cl-1){
      __syncthreads();   // hxch writes + pre/hs reads done
      if (tid == 0){
        int* c = &cnt[s*128 + g*16];   // 64B-padded per (step, group)
        __hip_atomic_fetch_add(c, 1, __ATOMIC_RELEASE, __HIP_MEMORY_SCOPE_AGENT);
        while (__hip_atomic_load(c, __ATOMIC_ACQUIRE, __HIP_MEMORY_SCOPE_AGENT) < NWG)
          __builtin_amdgcn_s_sleep(1);
      }
      __syncthreads();
    }
  }
  if (isPw){
    st_h[(size_t)b*HH + u] = h_st;
    st_c[(size_t)b*HH + u] = c_st;
    if (c0 + cl == TT){
      hT_out[(size_t)b*HH + u] = h_st;
      cT_out[(size_t)b*HH + u] = c_st;
    }
  }
}

// ------------------------------- launch ---------------------------------------
extern "C" void kernel_launch(void* const* d_in, const int* in_sizes, int n_in,
                              void* d_out, int out_size, void* d_ws, size_t ws_size,
                              hipStream_t stream)
{
  const float* x = nullptr; const float* masks = nullptr;
  const float* wih[4] = {}; const float* bih[4] = {}; const float* whh[4] = {};
  int nw = 0, nb = 0, nh = 0;
  for (int i = 0; i < n_in; ++i){
    const int sz = in_sizes[i];
    const float* p = (const float*)d_in[i];
    if      (sz == TT*BB*HH){ if (!x) x = p; }
    else if (sz == TT*BB)   { if (!masks) masks = p; }
    else if (sz == XH*HH)   { if (nw < 4) wih[nw++] = p; }
    else if (sz == XH)      { if (nb < 4) bih[nb++] = p; }
    else if (sz == GH*HH)   { if (nh < 4) whh[nh++] = p; }
  }
  float* out = (float*)d_out;
  if (!x || !masks || nw != 4 || nb != 4 || nh != 4){
    fill_sentinel_f<<<512, 256, 0, stream>>>(out, out_size, 777.0f);
    return;
  }

  char* ws = (char*)d_ws;
  size_t off = 0;
  auto alloc = [&](size_t bytes)->void*{
    void* p = ws + off; off += (bytes + 255) & ~(size_t)255; return p;
  };
  float*          act   = (float*)alloc((size_t)TT*BB*HH*4);             // 33.6 MB
  float*          xproj = (float*)alloc((size_t)CL*BB*XH*4);             // 50.3 MB
  unsigned int*   Wpk   = (unsigned int*)alloc((size_t)NWG*64*5*16*4*4); //  2.6 MB
  unsigned short* hxch  = (unsigned short*)alloc((size_t)2*BB*HH*2);     //  64 KB
  float*          st_h  = (float*)alloc((size_t)BB*HH*4);
  float*          st_c  = (float*)alloc((size_t)BB*HH*4);
  int*            cnt   = (int*)alloc((size_t)4*TT*128*4);               //  1 MB

  (void)hipMemsetAsync(cnt, 0, (size_t)4*TT*128*4, stream);

  float* hn = out + (size_t)TT*BB*HH;
  float* cn = hn + (size_t)4*BB*HH;

  for (int L = 0; L < 4; ++L){
    const int rev = L & 1;
    pack_whh<<<(NWG*64*5*16*4 + 255)/256, 256, 0, stream>>>(whh[L], Wpk);
    for (int c = 0; c < TT/CL; ++c){
      const int c0  = c*CL;
      const int tlo = rev ? (TT - c0 - CL) : c0;
      const float* Ain = (L == 0 ? x : act) + (size_t)tlo*BB*HH;
      gemm_valu<<<dim3(XH/VBN, (CL*BB)/VBM), 256, 0, stream>>>(
          Ain, wih[L], bih[L], xproj, CL*BB, XH, HH);

      lstm_scan_v3<<<NGRP*NWG, 512, 0, stream>>>(
          xproj, Wpk, masks,
          (L == 3) ? out : act,
          hn + (size_t)L*BB*HH, cn + (size_t)L*BB*HH,
          hxch, st_h, st_c,
          cnt + (size_t)L*TT*128,
          rev, c0, CL);
    }
  }
}

// Round 12
// 17911.546 us; speedup vs baseline: 16.6082x; 1.3017x over previous
//
#include <hip/hip_runtime.h>
#include <hip/hip_bf16.h>
#include <stdint.h>
#include <stddef.h>
#include <math.h>

#define HH 512
#define TT 512
#define BB 32
#define XH 3072   // 6*H
#define GH 2560   // 5*H
#define NWG 32    // unit-partition WGs per group
#define UPW 16    // units per WG
#define CL 128    // time-chunk length
#define NGRP 8    // batch groups (XCD-local)
#define RPG 4     // batch rows per group
#define HSTRIDE 520  // padded hs row stride in bf16 elements

typedef __attribute__((ext_vector_type(8))) short bf16x8;
typedef __attribute__((ext_vector_type(4))) float f32x4;

__device__ __forceinline__ float bf2f(unsigned short u){
  union{float f; unsigned int i;} v; v.i = ((unsigned int)u)<<16; return v.f;
}
__device__ __forceinline__ unsigned short f2bf(float f){
  union{float f; unsigned int i;} v; v.f=f;
  unsigned int x=v.i;
  return (unsigned short)((x + 0x7FFFu + ((x>>16)&1u))>>16);
}
__device__ __forceinline__ float sigm(float x){ return 1.f/(1.f+expf(-x)); }
__device__ __forceinline__ float tanh_f(float x){ return tanhf(x); }

__global__ void fill_sentinel_f(float* out, int n, float v){
  int i = blockIdx.x*blockDim.x + threadIdx.x;
  int stride = gridDim.x*blockDim.x;
  for (; i < n; i += stride) out[i] = v;
}

// ---------------- fp32 VALU GEMM: C[M,N] = A[M,K] @ W[N,K]^T + bias ----------
#define VBM 128
#define VBN 64
#define VBK 16

__global__ __launch_bounds__(256)
void gemm_valu(const float* __restrict__ A, const float* __restrict__ W,
               const float* __restrict__ bias, float* __restrict__ C,
               int M, int N, int K)
{
  __shared__ float As[VBK][VBM];
  __shared__ float Ws[VBK][VBN];
  const int tid = threadIdx.x;
  const int tx = tid & 15, ty = tid >> 4;
  const int gm = blockIdx.y, gn = blockIdx.x;
  float acc[8][4] = {};
  for (int k0 = 0; k0 < K; k0 += VBK){
    __syncthreads();
    {
      int row = tid >> 1, kc = (tid & 1)*8;
      const float* src = A + (size_t)(gm*VBM + row)*K + k0 + kc;
      float4 v0 = *(const float4*)(src);
      float4 v1 = *(const float4*)(src + 4);
      As[kc+0][row]=v0.x; As[kc+1][row]=v0.y; As[kc+2][row]=v0.z; As[kc+3][row]=v0.w;
      As[kc+4][row]=v1.x; As[kc+5][row]=v1.y; As[kc+6][row]=v1.z; As[kc+7][row]=v1.w;
    }
    {
      int row = tid >> 2, kc = (tid & 3)*4;
      float4 v = *(const float4*)(W + (size_t)(gn*VBN + row)*K + k0 + kc);
      Ws[kc+0][row]=v.x; Ws[kc+1][row]=v.y; Ws[kc+2][row]=v.z; Ws[kc+3][row]=v.w;
    }
    __syncthreads();
    #pragma unroll
    for (int kk = 0; kk < VBK; ++kk){
      float4 a0 = *(const float4*)&As[kk][ty*8];
      float4 a1 = *(const float4*)&As[kk][ty*8+4];
      float4 w  = *(const float4*)&Ws[kk][tx*4];
      float a[8] = {a0.x,a0.y,a0.z,a0.w,a1.x,a1.y,a1.z,a1.w};
      float wv[4] = {w.x,w.y,w.z,w.w};
      #pragma unroll
      for (int i=0;i<8;i++)
        #pragma unroll
        for (int j=0;j<4;j++)
          acc[i][j] = __builtin_fmaf(a[i], wv[j], acc[i][j]);
    }
  }
  #pragma unroll
  for (int i=0;i<8;i++){
    int row = gm*VBM + ty*8 + i;
    #pragma unroll
    for (int j=0;j<4;j++){
      int col = gn*VBN + tx*4 + j;
      C[(size_t)row*N + col] = acc[i][j] + bias[col];
    }
  }
}

// ---- scan v4: 8 groups x 32 WGs; weights in VGPRs (split-bf16), MFMA dot ----
// wave 0..4 = gate dot (one 16-unit MFMA N-tile), wave 5 = pointwise.
__global__ __launch_bounds__(512)
void lstm_scan_v4(const float* __restrict__ xp,          // [CL*B][6H] f32 chunk-local
                  const float* __restrict__ whh,         // [5H][H] f32
                  const float* __restrict__ masks,       // [T*B] f32
                  float* __restrict__ dst,               // [T*B][H] f32
                  float* __restrict__ hT_out, float* __restrict__ cT_out,
                  unsigned short* __restrict__ hxch,     // [2][B][H] bf16
                  float* __restrict__ st_h, float* __restrict__ st_c,
                  int* __restrict__ cnt,                 // [TT][128] ints (zeroed)
                  int reverse, int c0, int cl)
{
  __shared__ __align__(16) unsigned short hs[16*HSTRIDE];  // 16.6 KB
  __shared__ float pre[5][RPG][16];
  const int gid = blockIdx.x & 7;       // batch group (XCD-local by rr dispatch)
  const int wgi = blockIdx.x >> 3;      // unit-partition 0..31
  const int tid = threadIdx.x, wv = tid >> 6, lane = tid & 63;
  const int l15 = lane & 15, l4 = lane >> 4;

  // zero hs (rows 4..15 stay zero forever = M padding)
  for (int i = tid; i < 16*HSTRIDE; i += 512) hs[i] = 0;

  // dot waves: load B fragments (hi+lo split bf16) into registers, once.
  bf16x8 Bhi[16], Blo[16];
  if (wv < 5){
    const float* wrow = whh + ((size_t)(wv*HH + wgi*UPW + l15))*HH + l4*8;
    #pragma unroll
    for (int kc = 0; kc < 16; ++kc){
      float4 v0 = *(const float4*)(wrow + kc*32);
      float4 v1 = *(const float4*)(wrow + kc*32 + 4);
      float vv[8] = {v0.x,v0.y,v0.z,v0.w,v1.x,v1.y,v1.z,v1.w};
      bf16x8 hh, ll;
      #pragma unroll
      for (int j = 0; j < 8; ++j){
        unsigned short hb = f2bf(vv[j]);
        hh[j] = (short)hb;
        ll[j] = (short)f2bf(vv[j] - bf2f(hb));
      }
      Bhi[kc] = hh; Blo[kc] = ll;
    }
  }
  const bool isPw = (wv == 5);
  const int bl = l4 & 3, uu = l15;      // pw: row 0..3, unit 0..15
  const int b = gid*RPG + bl, u = wgi*UPW + uu;
  float c_st = 0.f, h_st = 0.f;
  if (isPw && c0 != 0){
    h_st = st_h[(size_t)b*HH + u];
    c_st = st_c[(size_t)b*HH + u];
  }
  __syncthreads();   // hs zeroed

  for (int sl = 0; sl < cl; ++sl){
    const int s  = c0 + sl;
    const int t  = reverse ? (TT-1-s) : s;
    const int lt = reverse ? (cl-1-sl) : sl;
    // pointwise prefetch (independent of h) — latency hides under dot
    float xi=0,xf=0,xo=0,xg=0,xj=0,xk=0,mm=0;
    if (isPw){
      const size_t xb = ((size_t)lt*BB + b)*XH + u;
      xi = xp[xb];        xf = xp[xb +   HH];
      xo = xp[xb + 2*HH]; xg = xp[xb + 3*HH];
      xj = xp[xb + 4*HH]; xk = xp[xb + 5*HH];
      mm = masks[t*BB + b];
    }
    if (s > 0){
      // restage this group's 4 h rows (4 KB bf16) into hs rows 0..3
      if (tid < 256){
        int row = tid >> 6, c8 = tid & 63;
        *(uint4*)&hs[row*HSTRIDE + c8*8] =
          *(const uint4*)(hxch + ((size_t)((s&1)^1)*BB + gid*RPG + row)*HH + c8*8);
      }
      __syncthreads();
      if (wv < 5){
        f32x4 a1 = {0.f,0.f,0.f,0.f}, a2 = {0.f,0.f,0.f,0.f};
        #pragma unroll
        for (int kc = 0; kc < 16; ++kc){
          bf16x8 A = *(const bf16x8*)&hs[l15*HSTRIDE + kc*32 + l4*8];
          a1 = __builtin_amdgcn_mfma_f32_16x16x32_bf16(A, Bhi[kc], a1, 0,0,0);
          a2 = __builtin_amdgcn_mfma_f32_16x16x32_bf16(A, Blo[kc], a2, 0,0,0);
        }
        if (l4 == 0){   // D rows 0..3 live in lanes 0..15
          #pragma unroll
          for (int r = 0; r < 4; ++r) pre[wv][r][l15] = a1[r] + a2[r];
        }
      }
    }
    __syncthreads();
    if (isPw){
      float p0=0,p1=0,p2=0,p3=0,p4=0;
      if (s > 0){
        p0 = pre[0][bl][uu]; p1 = pre[1][bl][uu]; p2 = pre[2][bl][uu];
        p3 = pre[3][bl][uu]; p4 = pre[4][bl][uu];
      }
      float ig = sigm(p0 + xi);
      float fg = sigm(p1 + xf + 1.0f);
      float og = sigm(p2 + xo);
      float tg = sigm(p3 + xg);
      float jg = tanh_f(p4 + xj);
      float cn = fg*c_st + ig*jg;
      cn = mm*cn + (1.f-mm)*c_st;
      float hn = tg*og*tanh_f(cn) + (1.f-tg)*xk;
      hn = mm*hn + (1.f-mm)*h_st;
      c_st = cn; h_st = hn;
      hxch[(size_t)(s&1)*BB*HH + (size_t)b*HH + u] = f2bf(hn);
      dst[((size_t)t*BB + b)*HH + u] = hn;
    }
    if (sl < cl-1){
      __syncthreads();   // all stores drained to L2 (vmcnt0 at barrier)
      if (tid == 0){
        int* c = &cnt[s*128 + gid*16];
        __hip_atomic_fetch_add(c, 1, __ATOMIC_RELEASE, __HIP_MEMORY_SCOPE_AGENT);
        while (__hip_atomic_load(c, __ATOMIC_ACQUIRE, __HIP_MEMORY_SCOPE_AGENT) < NWG)
          __builtin_amdgcn_s_sleep(1);
      }
      __syncthreads();
    }
  }
  if (isPw){
    st_h[(size_t)b*HH + u] = h_st;
    st_c[(size_t)b*HH + u] = c_st;
    if (c0 + cl == TT){
      hT_out[(size_t)b*HH + u] = h_st;
      cT_out[(size_t)b*HH + u] = c_st;
    }
  }
}

// ------------------------------- launch ---------------------------------------
extern "C" void kernel_launch(void* const* d_in, const int* in_sizes, int n_in,
                              void* d_out, int out_size, void* d_ws, size_t ws_size,
                              hipStream_t stream)
{
  const float* x = nullptr; const float* masks = nullptr;
  const float* wih[4] = {}; const float* bih[4] = {}; const float* whh[4] = {};
  int nw = 0, nb = 0, nh = 0;
  for (int i = 0; i < n_in; ++i){
    const int sz = in_sizes[i];
    const float* p = (const float*)d_in[i];
    if      (sz == TT*BB*HH){ if (!x) x = p; }
    else if (sz == TT*BB)   { if (!masks) masks = p; }
    else if (sz == XH*HH)   { if (nw < 4) wih[nw++] = p; }
    else if (sz == XH)      { if (nb < 4) bih[nb++] = p; }
    else if (sz == GH*HH)   { if (nh < 4) whh[nh++] = p; }
  }
  float* out = (float*)d_out;
  if (!x || !masks || nw != 4 || nb != 4 || nh != 4){
    fill_sentinel_f<<<512, 256, 0, stream>>>(out, out_size, 777.0f);
    return;
  }

  char* ws = (char*)d_ws;
  size_t off = 0;
  auto alloc = [&](size_t bytes)->void*{
    void* p = ws + off; off += (bytes + 255) & ~(size_t)255; return p;
  };
  float*          act   = (float*)alloc((size_t)TT*BB*HH*4);       // 33.6 MB
  float*          xproj = (float*)alloc((size_t)CL*BB*XH*4);       // 50.3 MB
  unsigned short* hxch  = (unsigned short*)alloc((size_t)2*BB*HH*2); // 64 KB
  float*          st_h  = (float*)alloc((size_t)BB*HH*4);
  float*          st_c  = (float*)alloc((size_t)BB*HH*4);
  int*            cnt   = (int*)alloc((size_t)4*TT*128*4);         //  1 MB

  (void)hipMemsetAsync(cnt, 0, (size_t)4*TT*128*4, stream);

  float* hn = out + (size_t)TT*BB*HH;
  float* cn = hn + (size_t)4*BB*HH;

  for (int L = 0; L < 4; ++L){
    const int rev = L & 1;
    for (int c = 0; c < TT/CL; ++c){
      const int c0  = c*CL;
      const int tlo = rev ? (TT - c0 - CL) : c0;
      const float* Ain = (L == 0 ? x : act) + (size_t)tlo*BB*HH;
      gemm_valu<<<dim3(XH/VBN, (CL*BB)/VBM), 256, 0, stream>>>(
          Ain, wih[L], bih[L], xproj, CL*BB, XH, HH);

      lstm_scan_v4<<<NGRP*NWG, 512, 0, stream>>>(
          xproj, whh[L], masks,
          (L == 3) ? out : act,
          hn + (size_t)L*BB*HH, cn + (size_t)L*BB*HH,
          hxch, st_h, st_c,
          cnt + (size_t)L*TT*128,
          rev, c0, CL);
    }
  }
}

// Round 13
// 13548.329 us; speedup vs baseline: 21.9569x; 1.3220x over previous
//
#include <hip/hip_runtime.h>
#include <hip/hip_bf16.h>
#include <stdint.h>
#include <stddef.h>
#include <math.h>

#define HH 512
#define TT 512
#define BB 32
#define XH 3072   // 6*H
#define GH 2560   // 5*H
#define NWG 32    // unit-partition WGs per group
#define UPW 16    // units per WG
#define CL 256    // time-chunk length (2 chunks per layer)
#define NGRP 8    // batch groups
#define RPG 4     // batch rows per group
#define HSTRIDE 520  // hs row stride in bf16 elements (words%32==4 -> even banks)
#define SCOPE __HIP_MEMORY_SCOPE_AGENT

typedef __attribute__((ext_vector_type(8))) short bf16x8;
typedef __attribute__((ext_vector_type(4))) float f32x4;

__device__ __forceinline__ float bf2f(unsigned short u){
  union{float f; unsigned int i;} v; v.i = ((unsigned int)u)<<16; return v.f;
}
__device__ __forceinline__ unsigned short f2bf(float f){
  union{float f; unsigned int i;} v; v.f=f;
  unsigned int x=v.i;
  return (unsigned short)((x + 0x7FFFu + ((x>>16)&1u))>>16);
}
__device__ __forceinline__ float sigm(float x){ return 1.f/(1.f+expf(-x)); }
__device__ __forceinline__ float tanh_f(float x){ return tanhf(x); }

__global__ void fill_sentinel_f(float* out, int n, float v){
  int i = blockIdx.x*blockDim.x + threadIdx.x;
  int stride = gridDim.x*blockDim.x;
  for (; i < n; i += stride) out[i] = v;
}

// ---------------- fp32 -> bf16 conversion (vectorized, grid-stride) ----------
__global__ void conv_f2bf(const float* __restrict__ in, unsigned short* __restrict__ out, int n){
  int i = (blockIdx.x*blockDim.x + threadIdx.x)*4;
  int stride = gridDim.x*blockDim.x*4;
  for (; i < n; i += stride){
    float4 v = *(const float4*)(in + i);
    ushort4 o; o.x=f2bf(v.x); o.y=f2bf(v.y); o.z=f2bf(v.z); o.w=f2bf(v.w);
    *(ushort4*)(out + i) = o;
  }
}

// ------- MFMA bf16 GEMM: C_f32[M,N] = A_bf16[M,K] @ Bt_bf16[N,K]^T + bias ----
#define BM 128
#define BN 128
#define BKK 32

__global__ __launch_bounds__(256)
void gemm_bt(const unsigned short* __restrict__ A, const unsigned short* __restrict__ Bt,
             const float* __restrict__ bias, float* __restrict__ C,
             int M, int N, int K)
{
  __shared__ unsigned short Alds[BM*BKK];
  __shared__ unsigned short Blds[BN*BKK];
  const int tid = threadIdx.x;
  const int lane = tid & 63;
  const int w = tid >> 6;
  const int gm = blockIdx.y, gn = blockIdx.x;
  const int wm = (w>>1)*64, wn = (w&1)*64;
  const int l15 = lane & 15, l4 = lane >> 4;
  f32x4 acc[4][4] = {};
  for (int k0 = 0; k0 < K; k0 += BKK){
    __syncthreads();
    #pragma unroll
    for (int it = 0; it < 2; ++it){
      int id2 = it*256 + tid;
      int row = id2 >> 2, kc = (id2 & 3)*8;   // 128 rows x 4 chunks of 8
      *(bf16x8*)&Alds[row*BKK + kc] = *(const bf16x8*)(A + (size_t)(gm*BM+row)*K + k0 + kc);
      *(bf16x8*)&Blds[row*BKK + kc] = *(const bf16x8*)(Bt + (size_t)(gn*BN+row)*K + k0 + kc);
    }
    __syncthreads();
    bf16x8 af[4], bfv[4];
    #pragma unroll
    for (int i=0;i<4;i++) af[i]  = *(const bf16x8*)&Alds[(wm + i*16 + l15)*BKK + l4*8];
    #pragma unroll
    for (int j=0;j<4;j++) bfv[j] = *(const bf16x8*)&Blds[(wn + j*16 + l15)*BKK + l4*8];
    #pragma unroll
    for (int i=0;i<4;i++)
      #pragma unroll
      for (int j=0;j<4;j++)
        acc[i][j] = __builtin_amdgcn_mfma_f32_16x16x32_bf16(af[i], bfv[j], acc[i][j], 0,0,0);
  }
  #pragma unroll
  for (int i=0;i<4;i++){
    int row0 = gm*BM + wm + i*16 + l4*4;
    #pragma unroll
    for (int j=0;j<4;j++){
      int col = gn*BN + wn + j*16 + l15;
      float bz = bias[col];
      #pragma unroll
      for (int r=0;r<4;r++)
        C[(size_t)(row0+r)*N + col] = acc[i][j][r] + bz;
    }
  }
}

// ---- scan v5: 8 groups x 32 WGs x 384 thr; weights in VGPRs, MFMA dot, -----
// ---- relaxed-spin barrier (single acquire-inv per step), xp prefetch-ahead --
__global__ __launch_bounds__(384)
void lstm_scan_v5(const float* __restrict__ xp,          // [CL*B][6H] f32 chunk-local
                  const float* __restrict__ whh,         // [5H][H] f32
                  const float* __restrict__ masks,       // [T*B] f32
                  unsigned short* __restrict__ abf,      // [T*B][H] bf16 activations
                  float* __restrict__ outF,              // [T*B][H] f32 (L==3) or null
                  float* __restrict__ hT_out, float* __restrict__ cT_out,
                  float* __restrict__ st_h, float* __restrict__ st_c,
                  int* __restrict__ cnt,                 // [TT][128] ints (zeroed)
                  int reverse, int c0, int cl)
{
  __shared__ __align__(16) unsigned short hs[16*HSTRIDE];  // 16.6 KB
  __shared__ float pre[5][RPG][16];
  const int gid = blockIdx.x & 7;       // batch group
  const int wgi = blockIdx.x >> 3;      // unit-partition 0..31
  const int tid = threadIdx.x, wv = tid >> 6, lane = tid & 63;
  const int l15 = lane & 15, l4 = lane >> 4;

  for (int i = tid; i < 16*HSTRIDE; i += 384) hs[i] = 0;

  // dot waves: B fragments (hi+lo split bf16) in registers, loaded once
  bf16x8 Bhi[16], Blo[16];
  if (wv < 5){
    const float* wrow = whh + ((size_t)(wv*HH + wgi*UPW + l15))*HH + l4*8;
    #pragma unroll
    for (int kc = 0; kc < 16; ++kc){
      float4 v0 = *(const float4*)(wrow + kc*32);
      float4 v1 = *(const float4*)(wrow + kc*32 + 4);
      float vv[8] = {v0.x,v0.y,v0.z,v0.w,v1.x,v1.y,v1.z,v1.w};
      bf16x8 hh, ll;
      #pragma unroll
      for (int j = 0; j < 8; ++j){
        unsigned short hb = f2bf(vv[j]);
        hh[j] = (short)hb;
        ll[j] = (short)f2bf(vv[j] - bf2f(hb));
      }
      Bhi[kc] = hh; Blo[kc] = ll;
    }
  }
  const bool isPw = (wv == 5);
  const int bl = l4 & 3, uu = l15;
  const int b = gid*RPG + bl, u = wgi*UPW + uu;
  float c_st = 0.f, h_st = 0.f;
  if (isPw && c0 != 0){
    h_st = st_h[(size_t)b*HH + u];
    c_st = st_c[(size_t)b*HH + u];
  }
  // prologue: prefetch xp for first step
  float cxi=0,cxf=0,cxo=0,cxg=0,cxj=0,cxk=0,cmm=0;
  if (isPw){
    const int lt0 = reverse ? (cl-1) : 0;
    const size_t xb = ((size_t)lt0*BB + b)*XH + u;
    cxi = xp[xb];        cxf = xp[xb +   HH];
    cxo = xp[xb + 2*HH]; cxg = xp[xb + 3*HH];
    cxj = xp[xb + 4*HH]; cxk = xp[xb + 5*HH];
    cmm = masks[(reverse ? (TT-1-c0) : c0)*BB + b];
  }
  __syncthreads();   // hs zeroed

  for (int sl = 0; sl < cl; ++sl){
    const int s = c0 + sl;
    const int t = reverse ? (TT-1-s) : s;
    // prefetch next step's xp early (latency hides under dot + barrier)
    float nxi=0,nxf=0,nxo=0,nxg=0,nxj=0,nxk=0,nmm=0;
    if (isPw && sl+1 < cl){
      const int lt1 = reverse ? (cl-2-sl) : (sl+1);
      const size_t xb = ((size_t)lt1*BB + b)*XH + u;
      nxi = xp[xb];        nxf = xp[xb +   HH];
      nxo = xp[xb + 2*HH]; nxg = xp[xb + 3*HH];
      nxj = xp[xb + 4*HH]; nxk = xp[xb + 5*HH];
      nmm = masks[(reverse ? (t-1) : (t+1))*BB + b];
    }
    if (s > 0){
      const int tp = reverse ? (t+1) : (t-1);
      if (tid < 256){
        int row = tid >> 6, c8 = tid & 63;
        *(uint4*)&hs[row*HSTRIDE + c8*8] =
          *(const uint4*)(abf + ((size_t)tp*BB + gid*RPG + row)*HH + c8*8);
      }
      __syncthreads();
      if (wv < 5){
        f32x4 a1 = {0.f,0.f,0.f,0.f}, a2 = {0.f,0.f,0.f,0.f};
        #pragma unroll
        for (int kc = 0; kc < 16; ++kc){
          bf16x8 A = *(const bf16x8*)&hs[l15*HSTRIDE + kc*32 + l4*8];
          a1 = __builtin_amdgcn_mfma_f32_16x16x32_bf16(A, Bhi[kc], a1, 0,0,0);
          a2 = __builtin_amdgcn_mfma_f32_16x16x32_bf16(A, Blo[kc], a2, 0,0,0);
        }
        if (l4 == 0){
          #pragma unroll
          for (int r = 0; r < 4; ++r) pre[wv][r][l15] = a1[r] + a2[r];
        }
      }
    }
    __syncthreads();
    if (isPw){
      float p0=0,p1=0,p2=0,p3=0,p4=0;
      if (s > 0){
        p0 = pre[0][bl][uu]; p1 = pre[1][bl][uu]; p2 = pre[2][bl][uu];
        p3 = pre[3][bl][uu]; p4 = pre[4][bl][uu];
      }
      float ig = sigm(p0 + cxi);
      float fg = sigm(p1 + cxf + 1.0f);
      float og = sigm(p2 + cxo);
      float tg = sigm(p3 + cxg);
      float jg = tanh_f(p4 + cxj);
      float cn = fg*c_st + ig*jg;
      cn = cmm*cn + (1.f-cmm)*c_st;
      float hn = tg*og*tanh_f(cn) + (1.f-tg)*cxk;
      hn = cmm*hn + (1.f-cmm)*h_st;
      c_st = cn; h_st = hn;
      abf[((size_t)t*BB + b)*HH + u] = f2bf(hn);
      if (outF) outF[((size_t)t*BB + b)*HH + u] = hn;
    }
    if (sl < cl-1){
      __syncthreads();   // abf stores drained (vmcnt0 at barrier)
      if (tid == 0){
        int* c = &cnt[s*128 + gid*16];
        __hip_atomic_fetch_add(c, 1, __ATOMIC_RELEASE, SCOPE);   // one L2 wb
        int it = 0;
        while (__hip_atomic_load(c, __ATOMIC_RELAXED, SCOPE) < NWG){
          if ((++it & 255) == 255){
            if (__hip_atomic_load(c, __ATOMIC_ACQUIRE, SCOPE) >= NWG) break;
          }
          __builtin_amdgcn_s_sleep(1);
        }
        (void)__hip_atomic_load(c, __ATOMIC_ACQUIRE, SCOPE);     // one L2 inv
      }
      __syncthreads();
    }
    if (isPw){
      cxi=nxi; cxf=nxf; cxo=nxo; cxg=nxg; cxj=nxj; cxk=nxk; cmm=nmm;
    }
  }
  if (isPw){
    st_h[(size_t)b*HH + u] = h_st;
    st_c[(size_t)b*HH + u] = c_st;
    if (c0 + cl == TT){
      hT_out[(size_t)b*HH + u] = h_st;
      cT_out[(size_t)b*HH + u] = c_st;
    }
  }
}

// ------------------------------- launch ---------------------------------------
extern "C" void kernel_launch(void* const* d_in, const int* in_sizes, int n_in,
                              void* d_out, int out_size, void* d_ws, size_t ws_size,
                              hipStream_t stream)
{
  const float* x = nullptr; const float* masks = nullptr;
  const float* wih[4] = {}; const float* bih[4] = {}; const float* whh[4] = {};
  int nw = 0, nb = 0, nh = 0;
  for (int i = 0; i < n_in; ++i){
    const int sz = in_sizes[i];
    const float* p = (const float*)d_in[i];
    if      (sz == TT*BB*HH){ if (!x) x = p; }
    else if (sz == TT*BB)   { if (!masks) masks = p; }
    else if (sz == XH*HH)   { if (nw < 4) wih[nw++] = p; }
    else if (sz == XH)      { if (nb < 4) bih[nb++] = p; }
    else if (sz == GH*HH)   { if (nh < 4) whh[nh++] = p; }
  }
  float* out = (float*)d_out;
  if (!x || !masks || nw != 4 || nb != 4 || nh != 4){
    fill_sentinel_f<<<512, 256, 0, stream>>>(out, out_size, 777.0f);
    return;
  }

  char* ws = (char*)d_ws;
  size_t off = 0;
  auto alloc = [&](size_t bytes)->void*{
    void* p = ws + off; off += (bytes + 255) & ~(size_t)255; return p;
  };
  unsigned short* xbf   = (unsigned short*)alloc((size_t)TT*BB*HH*2);  // 16.8 MB
  unsigned short* abf   = (unsigned short*)alloc((size_t)TT*BB*HH*2);  // 16.8 MB
  unsigned short* wbf   = (unsigned short*)alloc((size_t)XH*HH*2);     //  3.1 MB
  float*          xproj = (float*)alloc((size_t)CL*BB*XH*4);           // 100.7 MB
  float*          st_h  = (float*)alloc((size_t)BB*HH*4);
  float*          st_c  = (float*)alloc((size_t)BB*HH*4);
  int*            cnt   = (int*)alloc((size_t)4*TT*128*4);             //  1 MB

  (void)hipMemsetAsync(cnt, 0, (size_t)4*TT*128*4, stream);

  const int thr = 256;
  auto cgrid = [&](int n){ int g = (n/4 + thr - 1)/thr; return g > 2048 ? 2048 : g; };
  conv_f2bf<<<cgrid(TT*BB*HH), thr, 0, stream>>>(x, xbf, TT*BB*HH);

  float* hn = out + (size_t)TT*BB*HH;
  float* cn = hn + (size_t)4*BB*HH;

  for (int L = 0; L < 4; ++L){
    const int rev = L & 1;
    conv_f2bf<<<cgrid(XH*HH), thr, 0, stream>>>(wih[L], wbf, XH*HH);
    for (int c = 0; c < TT/CL; ++c){
      const int c0  = c*CL;
      const int tlo = rev ? (TT - c0 - CL) : c0;
      const unsigned short* Ain = (L == 0 ? xbf : abf) + (size_t)tlo*BB*HH;
      gemm_bt<<<dim3(XH/BN, (CL*BB)/BM), 256, 0, stream>>>(
          Ain, wbf, bih[L], xproj, CL*BB, XH, HH);

      lstm_scan_v5<<<NGRP*NWG, 384, 0, stream>>>(
          xproj, whh[L], masks, abf,
          (L == 3) ? out : nullptr,
          hn + (size_t)L*BB*HH, cn + (size_t)L*BB*HH,
          st_h, st_c,
          cnt + (size_t)L*TT*128,
          rev, c0, CL);
    }
  }
}